// Round 20
// baseline (186.718 us; speedup 1.0000x reference)
//
#include <hip/hip_runtime.h>

typedef unsigned int uint32;
typedef unsigned short u16;
typedef short s16x8 __attribute__((ext_vector_type(8)));
typedef float f32x4 __attribute__((ext_vector_type(4)));

#define DEVINL static __device__ __forceinline__
#define MFMA16(a, b, c) __builtin_amdgcn_mfma_f32_16x16x32_bf16(a, b, c, 0, 0, 0)

DEVINL float bf2f(u16 u){ return __uint_as_float(((uint32)u) << 16); }
DEVINL u16 f2bf(float f){
  uint32 u = __float_as_uint(f);
  u += 0x7fffu + ((u >> 16) & 1u);   // RNE
  return (u16)(u >> 16);
}
DEVINL uint32 pack2(float a, float b){
  return (uint32)f2bf(a) | (((uint32)f2bf(b)) << 16);
}

// ---------------- dtype detector (proven) ----------------
__global__ void detect_k(const uint32* __restrict__ x, uint32* __restrict__ flag){
  const int lane = threadIdx.x;   // 64 threads
  int sane = 0;
  for (int i = 0; i < 32; ++i){
    uint32 u = x[i * 64 + lane];
    uint32 e = (u >> 7) & 0xffu;
    sane += (e >= 100u && e <= 150u) ? 1 : 0;
  }
  for (int off = 32; off >= 1; off >>= 1) sane += __shfl_xor(sane, off);
  if (lane == 0) *flag = (sane > 1024) ? 1u : 0u;   // 1 = bf16, 0 = fp32
}

// ---------------- all weights -> f32 blob (merged dual-mode) ----------------
__global__ void cvtall_k(const void* s0, const void* s1, const void* s2,
                         const void* s3, const void* s4, const void* s5,
                         const void* s6, const void* s7, const void* s8,
                         float* __restrict__ wb, const uint32* __restrict__ flag)
{
  const bool bf = (*flag != 0u);
  const int i = blockIdx.x * 256 + threadIdx.x;
  if (i >= 196864) return;
  const void* s; int j;
  if      (i < 4096)   { s = s0; j = i; }
  else if (i < 8192)   { s = s1; j = i - 4096; }
  else if (i < 12288)  { s = s2; j = i - 8192; }
  else if (i < 49152)  { s = s3; j = i - 12288; }
  else if (i < 49216)  { s = s4; j = i - 49152; }
  else if (i < 122944) { s = s5; j = i - 49216; }
  else if (i < 123072) { s = s6; j = i - 122944; }
  else if (i < 196800) { s = s7; j = i - 123072; }
  else                 { s = s8; j = i - 196800; }
  wb[i] = bf ? bf2f(((const u16*)s)[j]) : ((const float*)s)[j];
}

// ---------------- x -> bf16 convert (fp32 mode only; stride-8 grid 512) ----------------
__global__ __launch_bounds__(256)
void xcvt_k(const void* __restrict__ x, u16* __restrict__ xb,
            const uint32* __restrict__ flag)
{
  if (*flag != 0u) return;
  const int t = blockIdx.x * 256 + threadIdx.x;    // 131072 threads
#pragma unroll 1
  for (int k = 0; k < 8; ++k){
    const size_t i0 = ((size_t)k * 131072 + t) * 8;
    const float4 f0 = ((const float4*)x)[i0 / 4];
    const float4 f1 = ((const float4*)x)[i0 / 4 + 1];
    uint4 o;
    o.x = pack2(f0.x, f0.y); o.y = pack2(f0.z, f0.w);
    o.z = pack2(f1.x, f1.y); o.w = pack2(f1.z, f1.w);
    *(uint4*)(xb + i0) = o;
  }
}

// ---------------- pack: gt (row-PERMUTED hi/lo) + vt + conv weights ----------------
// Row permute: gt'[nt*16+lk*4+reg] = G[lk*16+nt*4+reg] so attn lane lk owns the
// CONTIGUOUS d-slice [lk*16, lk*16+16) -> score phase reads x via b128 like y-phase.
// bb: gt[0,8192) vt[8192,12288) vlo[12288,16384) w1pk[16384,53248)
//     w2pk[53248,126976) w3pk[126976,200704)
__global__ void pack_k(const float* __restrict__ wb, u16* __restrict__ bb){
  int i = blockIdx.x * 256 + threadIdx.x;   // grid exact: 768*256 = 196608
  if (i < 4096){                                      // gt hi+lo (permuted rows)
    const int d = i >> 6, c = i & 63;
    const int ds = ((d >> 2) & 3) * 16 + (d >> 4) * 4 + (d & 3);
    const float* __restrict__ K = wb + 4096;
    const float* __restrict__ Q = wb;
    float s = 0.f;
#pragma unroll
    for (int e = 0; e < 64; ++e) s = fmaf(K[ds * 64 + e], Q[c * 64 + e], s);
    const u16 hi = f2bf(s);
    bb[i] = hi;
    bb[4096 + i] = f2bf(s - bf2f(hi));
    return;
  }
  i -= 4096;
  if (i < 4096){                                      // vt hi: vt[o][c] = V[c][o]
    const int o = i >> 6, c = i & 63;
    bb[8192 + i] = f2bf(wb[8192 + c * 64 + o]);
    return;
  }
  i -= 4096;
  if (i < 4096){                                      // vt lo (unused)
    const int o = i >> 6, c = i & 63;
    const float v = wb[8192 + c * 64 + o];
    bb[12288 + i] = f2bf(v - bf2f(f2bf(v)));
    return;
  }
  i -= 4096;
  if (i < 36864){                                     // w1pk (18 chunks)
    const int chunk = i >> 11, rr = i & 2047, co = rr >> 5, kkp = rr & 31;
    const int slot = (kkp >> 3) ^ ((co >> 1) & 3), kk = slot * 8 + (kkp & 7);
    const int tap = chunk >> 1, ci = (chunk & 1) * 32 + kk;
    bb[16384 + i] = f2bf(wb[12288 + (tap * 64 + ci) * 64 + co]);
    return;
  }
  i -= 36864;
  if (i < 73728){                                     // w2pk [2 halves][18 chunks]
    const int half = i / 36864, i2 = i - half * 36864;
    const int chunk = i2 >> 11, rr = i2 & 2047, co = rr >> 5, kkp = rr & 31;
    const int slot = (kkp >> 3) ^ ((co >> 1) & 3), kk = slot * 8 + (kkp & 7);
    const int tap = chunk >> 1, ci = (chunk & 1) * 32 + kk;
    bb[53248 + i] = f2bf(wb[49216 + (tap * 64 + ci) * 128 + half * 64 + co]);
    return;
  }
  i -= 73728;
  {                                                   // w3pk (36 chunks: tap*4 + ci_chunk)
    const int chunk = i >> 11, rr = i & 2047, co = rr >> 5, kkp = rr & 31;
    const int slot = (kkp >> 3) ^ ((co >> 1) & 3), kk = slot * 8 + (kkp & 7);
    const int tap = chunk >> 2, ci = (chunk & 3) * 32 + kk;
    bb[126976 + i] = f2bf(wb[123072 + (tap * 128 + ci) * 64 + co]);
  }
}

// ---------------- halo staging into swizzled LDS ----------------
template<int ROWS, int CIN, int STRIDE>
DEVINL void stage_tile(const u16* __restrict__ img_base, int h0, int w0, u16* lds){
  constexpr int CH8 = CIN / 8;
  constexpr int NCH = ROWS * 66 * CH8;
  for (int idx = threadIdx.x; idx < NCH; idx += 256){
    const int row  = idx / (66 * CH8);
    const int rem  = idx - row * 66 * CH8;
    const int col  = rem / CH8;
    const int slot = rem - col * CH8;
    const int hi = h0 + row - 1, wi = w0 + col - 1;
    uint4 v = make_uint4(0u, 0u, 0u, 0u);
    if (hi >= 0 && hi < 128 && wi >= 0 && wi < 128)
      v = *(const uint4*)(img_base + (size_t)(hi * 128 + wi) * STRIDE + slot * 8);
    const int dst = (row * 66 + col) * CIN + ((slot ^ (col & 7)) << 3);
    *(uint4*)(lds + dst) = v;
  }
}

// ---------------- coalesced conv epilogue (TROWS=2, runtime out dtype) ----------------
template<int COUT_FULL, bool RES>
DEVINL void conv_epilogue2(f32x4 acc[2][4], u16* scratch, const u16* __restrict__ res,
                           void* __restrict__ out, int img, int h0, int w0, int co0,
                           int wv, int l15, int lk, int mout)
{
  float* tl = (float*)scratch;            // 128 px x 72 f32 = 36864 B
  const int lane = threadIdx.x & 63;
  __syncthreads();                        // all halo reads done (tl aliases halo)
  const int pbase = (wv >> 1) * 64 + (wv & 1) * 32;
#pragma unroll
  for (int at = 0; at < 2; ++at)
#pragma unroll
    for (int nt = 0; nt < 4; ++nt)
#pragma unroll
      for (int reg = 0; reg < 4; ++reg)
        tl[(pbase + at * 16 + lk * 4 + reg) * 72 + nt * 16 + l15] =
            fmaxf(acc[at][nt][reg], 0.f);
  __syncthreads();

  if (mout == 0){
#pragma unroll
    for (int k = 0; k < 8; ++k){
      const int pxl = k * 16 + wv * 4 + (lane >> 4);
      const int c4  = (lane & 15) * 4;
      const int row = pxl >> 6, col = pxl & 63;
      const size_t gpx = (size_t)img * 16384 + (size_t)(h0 + row) * 128 + w0 + col;
      float4 v = *(const float4*)(tl + pxl * 72 + c4);
      if (RES){
        const uint2 r = *(const uint2*)(res + gpx * 64 + c4);
        v.x += bf2f((u16)(r.x & 0xffff)); v.y += bf2f((u16)(r.x >> 16));
        v.z += bf2f((u16)(r.y & 0xffff)); v.w += bf2f((u16)(r.y >> 16));
      }
      *(float4*)((float*)out + gpx * 64 + c4) = v;
    }
  } else {
#pragma unroll
    for (int j = 0; j < 4; ++j){
      const int pxl = j * 32 + wv * 8 + (lane >> 3);
      const int c8  = (lane & 7) * 8;
      const int row = pxl >> 6, col = pxl & 63;
      const size_t gpx = (size_t)img * 16384 + (size_t)(h0 + row) * 128 + w0 + col;
      const float* tp = tl + pxl * 72 + c8;
      const float4 a = *(const float4*)tp;
      const float4 b = *(const float4*)(tp + 4);
      float v0=a.x, v1=a.y, v2=a.z, v3=a.w, v4=b.x, v5=b.y, v6=b.z, v7=b.w;
      if (RES){
        const uint4 r = *(const uint4*)(res + gpx * 64 + c8);
        v0 += bf2f((u16)(r.x & 0xffff)); v1 += bf2f((u16)(r.x >> 16));
        v2 += bf2f((u16)(r.y & 0xffff)); v3 += bf2f((u16)(r.y >> 16));
        v4 += bf2f((u16)(r.z & 0xffff)); v5 += bf2f((u16)(r.z >> 16));
        v6 += bf2f((u16)(r.w & 0xffff)); v7 += bf2f((u16)(r.w >> 16));
      }
      uint4 o;
      o.x = pack2(v0, v1); o.y = pack2(v2, v3);
      o.z = pack2(v4, v5); o.w = pack2(v6, v7);
      *(uint4*)((u16*)out + gpx * COUT_FULL + co0 + c8) = o;
    }
  }
}

// ---------------- fused 3x3 pixel attention (permuted-G b128 score phase) ----------------
// racc[nt][reg] = r[d = lk*16 + nt*4 + reg][pxm] (via row-permuted gt). Score and
// y phases now read the SAME 18 b128 LDS words per lane.
__global__ __launch_bounds__(256, 4)
void attn_mfma(const u16* __restrict__ xraw, const u16* __restrict__ xcv,
               const u16* __restrict__ gt, const u16* __restrict__ vt,
               u16* __restrict__ tb, const uint32* __restrict__ flag)
{
  __shared__ __align__(16) u16 xh[3 * 66 * 64];
  u16* yl  = xh;                   // aliases halo row 0
  u16* yl2 = xh + 2 * 66 * 64;     // aliases halo row 2
  const int bx0 = blockIdx.x;
  const int bx = (bx0 & 7) * 256 + (bx0 >> 3);   // XCD-chunked swizzle (2048 wgs)
  const int img = bx >> 8, h = (bx >> 1) & 127, w0 = (bx & 1) * 64;
  const int p0 = img * 16384 + h * 128 + w0;
  const u16* __restrict__ xsrc = (*flag != 0u) ? xraw : xcv;
  stage_tile<3, 64, 64>(xsrc + (size_t)img * 16384 * 64, h, w0, xh);
  __syncthreads();   // sync1

  const int lane = threadIdx.x & 63, wv = threadIdx.x >> 6;
  const int l15 = lane & 15, lk = lane >> 4;
  const int pxm = wv * 16 + l15;

  // ---- QK^T (swapped, permuted rows) ----
  f32x4 racc[4];
#pragma unroll
  for (int nt = 0; nt < 4; ++nt) racc[nt] = (f32x4){0.f, 0.f, 0.f, 0.f};
#pragma unroll
  for (int half = 0; half < 2; ++half){
#pragma unroll
    for (int ks = 0; ks < 2; ++ks){
      const int colq = pxm + 1;
      const int slot = ks * 4 + lk;
      const s16x8 bx_ = *(const s16x8*)&xh[(66 + colq) * 64 + ((slot ^ (colq & 7)) << 3)];
#pragma unroll
      for (int nt = 0; nt < 4; ++nt){
        const s16x8 ag = *(const s16x8*)(gt + half * 4096 +
                          (size_t)(nt * 16 + l15) * 64 + ks * 32 + lk * 8);
        racc[nt] = MFMA16(ag, bx_, racc[nt]);
      }
    }
  }

  // ---- scores: lane sums its contiguous 16 d via the same b128 reads as y ----
  float sc[9];
#pragma unroll
  for (int n = 0; n < 9; ++n){
    const int tr = n / 3, tc = n % 3;
    const int col = pxm + tc;
    const u16* xr = &xh[(tr * 66 + col) * 64];
    float s = 0.f;
#pragma unroll
    for (int sl = 0; sl < 2; ++sl){
      const int slot = lk * 2 + sl;
      const s16x8 v = *(const s16x8*)&xr[(slot ^ (col & 7)) << 3];
#pragma unroll
      for (int jj = 0; jj < 8; ++jj){
        const int j = sl * 8 + jj;           // d = lk*16 + j, j = nt*4+reg
        s = fmaf(bf2f((u16)v[jj]), racc[j >> 2][j & 3], s);
      }
    }
    sc[n] = s;
  }
#pragma unroll
  for (int n = 0; n < 9; ++n){
    sc[n] += __shfl_xor(sc[n], 16);
    sc[n] += __shfl_xor(sc[n], 32);
  }

  float mx = sc[0];
#pragma unroll
  for (int n = 1; n < 9; ++n) mx = fmaxf(mx, sc[n]);
  float sum = 0.f;
#pragma unroll
  for (int n = 0; n < 9; ++n){
    const float e = __expf(sc[n] - mx);
    sc[n] = e; sum += e;
  }
  const float inv = 1.f / sum;
#pragma unroll
  for (int n = 0; n < 9; ++n) sc[n] *= inv;

  // ---- y: same 18 b128 reads, alpha-weighted ----
  float y[16];
#pragma unroll
  for (int j = 0; j < 16; ++j) y[j] = 0.f;
#pragma unroll
  for (int n = 0; n < 9; ++n){
    const int tr = n / 3, tc = n % 3;
    const int col = pxm + tc;
    const u16* xr = &xh[(tr * 66 + col) * 64];
    const float a = sc[n];
#pragma unroll
    for (int sl = 0; sl < 2; ++sl){
      const int slot = lk * 2 + sl;
      const s16x8 v = *(const s16x8*)&xr[(slot ^ (col & 7)) << 3];
#pragma unroll
      for (int j = 0; j < 8; ++j)
        y[sl * 8 + j] = fmaf(a, bf2f((u16)v[j]), y[sl * 8 + j]);
    }
  }

  __syncthreads();   // sync3: all xh row-0/2 reads complete before alias writes

#pragma unroll
  for (int sl = 0; sl < 2; ++sl){
    uint32 hwd[4], lwd[4];
#pragma unroll
    for (int j = 0; j < 4; ++j){
      const float a = y[sl * 8 + 2 * j], b = y[sl * 8 + 2 * j + 1];
      const u16 ha = f2bf(a), hb = f2bf(b);
      hwd[j] = (uint32)ha | ((uint32)hb << 16);
      lwd[j] = (uint32)f2bf(a - bf2f(ha)) | ((uint32)f2bf(b - bf2f(hb)) << 16);
    }
    const int slot = lk * 2 + sl;
    const int off = pxm * 64 + ((slot ^ (pxm & 7)) << 3);
    *(uint4*)&yl [off] = make_uint4(hwd[0], hwd[1], hwd[2], hwd[3]);
    *(uint4*)&yl2[off] = make_uint4(lwd[0], lwd[1], lwd[2], lwd[3]);
  }

  __syncthreads();   // sync4: y visible before PV reads

  f32x4 tacc[4];
#pragma unroll
  for (int nt = 0; nt < 4; ++nt) tacc[nt] = (f32x4){0.f, 0.f, 0.f, 0.f};
#pragma unroll
  for (int half = 0; half < 2; ++half){
    const u16* yb = half ? yl2 : yl;
#pragma unroll
    for (int ks = 0; ks < 2; ++ks){
      const int px = wv * 16 + l15;
      const int slot = ks * 4 + lk;
      const s16x8 af = *(const s16x8*)&yb[px * 64 + ((slot ^ (px & 7)) << 3)];
#pragma unroll
      for (int nt = 0; nt < 4; ++nt){
        const s16x8 bf = *(const s16x8*)(vt + (size_t)(nt * 16 + l15) * 64 + ks * 32 + lk * 8);
        tacc[nt] = MFMA16(af, bf, tacc[nt]);
      }
    }
  }
#pragma unroll
  for (int nt = 0; nt < 4; ++nt){
#pragma unroll
    for (int reg = 0; reg < 4; ++reg){
      const int pxo = wv * 16 + lk * 4 + reg;
      const int co = nt * 16 + l15;
      const int col = pxo + 1;
      const int elem = (66 + col) * 64 + (((co >> 3) ^ (col & 7)) << 3) + (co & 7);
      tb[(size_t)(p0 + pxo) * 64 + co] = f2bf(bf2f(xh[elem]) + tacc[nt][reg]);
    }
  }
}

// ---------------- conv1/conv2 (CIN=64): TROWS=2, A from LDS halo, B in registers ----------------
template<int COUT_FULL, bool RES>
__global__ __launch_bounds__(256)
void conv_mfma(const u16* __restrict__ in, const u16* __restrict__ wpk,
               const float* __restrict__ bias, const u16* __restrict__ res,
               void* __restrict__ out)
{
  __shared__ __align__(16) u16 xh[18432];         // 36864 B: halo 4x66x64 + epi scratch

  const int bx0 = blockIdx.x;
  const int bx  = (bx0 & 7) * 128 + (bx0 >> 3);   // XCD-chunked swizzle (1024 wgs)
  const int img = bx >> 7;
  const int rem = bx & 127;
  const int h0  = (rem >> 1) * 2;
  const int w0  = (rem & 1) * 64;
  const int co0 = blockIdx.y * 64;
  const u16* __restrict__ wp = wpk + (size_t)blockIdx.y * 18 * 2048;

  stage_tile<4, 64, 64>(in + (size_t)img * 16384 * 64, h0, w0, xh);
  __syncthreads();

  const int lane = threadIdx.x & 63, wv = threadIdx.x >> 6;
  const int l15 = lane & 15, lk = lane >> 4;
  const int r   = wv >> 1, c0l = (wv & 1) * 32;

  f32x4 acc[2][4];
#pragma unroll
  for (int nt = 0; nt < 4; ++nt){
    const float b = bias[co0 + nt * 16 + l15];
#pragma unroll
    for (int at = 0; at < 2; ++at) acc[at][nt] = (f32x4){b, b, b, b};
  }

  auto loadB = [&](int ck, s16x8* bb){
#pragma unroll
    for (int nt = 0; nt < 4; ++nt){
      const int co = nt * 16 + l15;
      bb[nt] = *(const s16x8*)(wp + (size_t)ck * 2048 + co * 32 +
                               ((lk ^ ((co >> 1) & 3)) << 3));
    }
  };
  auto doM = [&](int it, s16x8* bb){
    const int tap = it >> 1, ks = it & 1;
    const int tr = tap / 3, tc = tap - tr * 3;
    const int slot = ks * 4 + lk;
    s16x8 av[2];
#pragma unroll
    for (int at = 0; at < 2; ++at){
      const int col = c0l + at * 16 + l15 + tc;
      av[at] = *(const s16x8*)&xh[((r + tr) * 66 + col) * 64 + ((slot ^ (col & 7)) << 3)];
    }
#pragma unroll
    for (int at = 0; at < 2; ++at)
#pragma unroll
      for (int nt = 0; nt < 4; ++nt)
        acc[at][nt] = MFMA16(av[at], bb[nt], acc[at][nt]);
  };

  s16x8 b0[4], b1[4];
  loadB(0, b0);
  loadB(1, b1);
#pragma unroll 1
  for (int it = 0; it < 18; it += 2){
    doM(it, b0);
    if (it + 2 < 18) loadB(it + 2, b0);
    doM(it + 1, b1);
    if (it + 3 < 18) loadB(it + 3, b1);
  }

  conv_epilogue2<COUT_FULL, RES>(acc, xh, res, out, img, h0, w0, co0, wv, l15, lk, 1);
}

// ---------------- conv3 (CIN=128): TROWS=2, two ci-half phases, merged out-dtype ----------------
__global__ __launch_bounds__(256)
void conv3_mfma(const u16* __restrict__ in, const u16* __restrict__ wpk,
                const float* __restrict__ bias, const u16* __restrict__ res,
                void* __restrict__ out, const uint32* __restrict__ flag)
{
  const int mout = (*flag != 0u) ? 1 : 0;
  __shared__ __align__(16) u16 xh[18432];         // 36864 B

  const int bx0 = blockIdx.x;
  const int bx  = (bx0 & 7) * 128 + (bx0 >> 3);   // XCD-chunked swizzle (1024 wgs)
  const int img = bx >> 7;
  const int rem = bx & 127;
  const int h0  = (rem >> 1) * 2;
  const int w0  = (rem & 1) * 64;

  const int lane = threadIdx.x & 63, wv = threadIdx.x >> 6;
  const int l15 = lane & 15, lk = lane >> 4;
  const int r   = wv >> 1, c0l = (wv & 1) * 32;

  f32x4 acc[2][4];
#pragma unroll
  for (int nt = 0; nt < 4; ++nt){
    const float b = bias[nt * 16 + l15];
#pragma unroll
    for (int at = 0; at < 2; ++at) acc[at][nt] = (f32x4){b, b, b, b};
  }

  auto loadB = [&](int ck, s16x8* bb){
#pragma unroll
    for (int nt = 0; nt < 4; ++nt){
      const int co = nt * 16 + l15;
      bb[nt] = *(const s16x8*)(wpk + (size_t)ck * 2048 + co * 32 +
                               ((lk ^ ((co >> 1) & 3)) << 3));
    }
  };
  auto doM = [&](int it, s16x8* bb){
    const int tap = it >> 1, ks = it & 1;
    const int tr = tap / 3, tc = tap - tr * 3;
    const int slot = ks * 4 + lk;
    s16x8 av[2];
#pragma unroll
    for (int at = 0; at < 2; ++at){
      const int col = c0l + at * 16 + l15 + tc;
      av[at] = *(const s16x8*)&xh[((r + tr) * 66 + col) * 64 + ((slot ^ (col & 7)) << 3)];
    }
#pragma unroll
    for (int at = 0; at < 2; ++at)
#pragma unroll
      for (int nt = 0; nt < 4; ++nt)
        acc[at][nt] = MFMA16(av[at], bb[nt], acc[at][nt]);
  };
  auto chunkOf = [&](int it, int half){
    return ((it >> 1) << 2) + half * 2 + (it & 1);   // tap*4 + half*2 + ks
  };

#pragma unroll 1
  for (int half = 0; half < 2; ++half){
    if (half) __syncthreads();            // all waves' reads of phase-0 halo done
    stage_tile<4, 64, 128>(in + (size_t)img * 16384 * 128 + half * 64, h0, w0, xh);
    __syncthreads();

    s16x8 b0[4], b1[4];
    loadB(chunkOf(0, half), b0);
    loadB(chunkOf(1, half), b1);
#pragma unroll 1
    for (int it = 0; it < 18; it += 2){
      doM(it, b0);
      if (it + 2 < 18) loadB(chunkOf(it + 2, half), b0);
      doM(it + 1, b1);
      if (it + 3 < 18) loadB(chunkOf(it + 3, half), b1);
    }
  }

  conv_epilogue2<64, true>(acc, xh, res, out, img, h0, w0, 0, wv, l15, lk, mout);
}

extern "C" void kernel_launch(void* const* d_in, const int* in_sizes, int n_in,
                              void* d_out, int out_size, void* d_ws, size_t ws_size,
                              hipStream_t stream)
{
  (void)in_sizes; (void)n_in; (void)out_size; (void)ws_size;

  char* ws = (char*)d_ws;
  float*  wblob = (float*)ws;                            // 196864 f32
  uint32* flag  = (uint32*)(ws + 983040);
  u16*    bb    = (u16*)(ws + (1u << 20));               // bf16 blob (200704 u16)
  u16*    gt   = bb;                                     // [2][64][64] hi/lo (permuted)
  u16*    vt   = bb + 8192;                              // [64][64] hi
  u16*    w1pk = bb + 16384;                             // 18 x 4KB chunks
  u16*    w2pk = bb + 53248;                             // 2 x 18 x 4KB
  u16*    w3pk = bb + 126976;                            // 36 x 4KB

  u16*   c2 = (u16*)(ws + (size_t)2097152);              // 33.55 MB
  u16*   tb = (u16*)(ws + (size_t)35651584);             // 16.78 MB
  u16*   xb = (u16*)(ws + (size_t)52428800);             // 16.78 MB (fp32 mode)
  u16*   c1 = (u16*)(ws + (size_t)52428800);             // 16.78 MB (after attn)

  detect_k<<<1, 64, 0, stream>>>((const uint32*)d_in[0], flag);

  cvtall_k<<<769, 256, 0, stream>>>(d_in[1], d_in[2], d_in[3], d_in[4], d_in[5],
                                    d_in[6], d_in[7], d_in[8], d_in[9], wblob, flag);

  xcvt_k<<<512, 256, 0, stream>>>(d_in[0], xb, flag);    // fp32 mode only

  pack_k<<<768, 256, 0, stream>>>(wblob, bb);            // gt (permuted) + vt + conv W

  attn_mfma<<<2048, 256, 0, stream>>>((const u16*)d_in[0], xb, gt, vt, tb, flag);

  conv_mfma<64, false><<<dim3(1024, 1), 256, 0, stream>>>(
      tb, w1pk, wblob + 49152, nullptr, c1);
  conv_mfma<128, false><<<dim3(1024, 2), 256, 0, stream>>>(
      c1, w2pk, wblob + 122944, nullptr, c2);
  conv3_mfma<<<1024, 256, 0, stream>>>(
      c2, w3pk, wblob + 196800, tb, d_out, flag);
}

// Round 21
// 134.882 us; speedup vs baseline: 1.3843x; 1.3843x over previous
//
#include <hip/hip_runtime.h>

typedef unsigned int uint32;
typedef unsigned short u16;
typedef short s16x8 __attribute__((ext_vector_type(8)));
typedef short s16x4 __attribute__((ext_vector_type(4)));
typedef float f32x4 __attribute__((ext_vector_type(4)));

#define DEVINL static __device__ __forceinline__
#define MFMA16(a, b, c) __builtin_amdgcn_mfma_f32_16x16x32_bf16(a, b, c, 0, 0, 0)

DEVINL float bf2f(u16 u){ return __uint_as_float(((uint32)u) << 16); }
DEVINL u16 f2bf(float f){
  uint32 u = __float_as_uint(f);
  u += 0x7fffu + ((u >> 16) & 1u);   // RNE
  return (u16)(u >> 16);
}
DEVINL uint32 pack2(float a, float b){
  return (uint32)f2bf(a) | (((uint32)f2bf(b)) << 16);
}

// ---------------- dtype detector (proven) ----------------
__global__ void detect_k(const uint32* __restrict__ x, uint32* __restrict__ flag){
  const int lane = threadIdx.x;   // 64 threads
  int sane = 0;
  for (int i = 0; i < 32; ++i){
    uint32 u = x[i * 64 + lane];
    uint32 e = (u >> 7) & 0xffu;
    sane += (e >= 100u && e <= 150u) ? 1 : 0;
  }
  for (int off = 32; off >= 1; off >>= 1) sane += __shfl_xor(sane, off);
  if (lane == 0) *flag = (sane > 1024) ? 1u : 0u;   // 1 = bf16, 0 = fp32
}

// ---------------- all weights -> f32 blob (merged dual-mode) ----------------
__global__ void cvtall_k(const void* s0, const void* s1, const void* s2,
                         const void* s3, const void* s4, const void* s5,
                         const void* s6, const void* s7, const void* s8,
                         float* __restrict__ wb, const uint32* __restrict__ flag)
{
  const bool bf = (*flag != 0u);
  const int i = blockIdx.x * 256 + threadIdx.x;
  if (i >= 196864) return;
  const void* s; int j;
  if      (i < 4096)   { s = s0; j = i; }
  else if (i < 8192)   { s = s1; j = i - 4096; }
  else if (i < 12288)  { s = s2; j = i - 8192; }
  else if (i < 49152)  { s = s3; j = i - 12288; }
  else if (i < 49216)  { s = s4; j = i - 49152; }
  else if (i < 122944) { s = s5; j = i - 49216; }
  else if (i < 123072) { s = s6; j = i - 122944; }
  else if (i < 196800) { s = s7; j = i - 123072; }
  else                 { s = s8; j = i - 196800; }
  wb[i] = bf ? bf2f(((const u16*)s)[j]) : ((const float*)s)[j];
}

// ---------------- x -> bf16 convert (fp32 mode only; stride-8 grid 512) ----------------
__global__ __launch_bounds__(256)
void xcvt_k(const void* __restrict__ x, u16* __restrict__ xb,
            const uint32* __restrict__ flag)
{
  if (*flag != 0u) return;
  const int t = blockIdx.x * 256 + threadIdx.x;    // 131072 threads
#pragma unroll 1
  for (int k = 0; k < 8; ++k){
    const size_t i0 = ((size_t)k * 131072 + t) * 8;
    const float4 f0 = ((const float4*)x)[i0 / 4];
    const float4 f1 = ((const float4*)x)[i0 / 4 + 1];
    uint4 o;
    o.x = pack2(f0.x, f0.y); o.y = pack2(f0.z, f0.w);
    o.z = pack2(f1.x, f1.y); o.w = pack2(f1.z, f1.w);
    *(uint4*)(xb + i0) = o;
  }
}

// ---------------- pack: gt (IDENTITY rows, hi/lo) + vt + conv weights ----------------
// r20 lesson: do NOT permute G rows to make score/y reads identical — the compiler
// then keeps 72 VGPRs of x live across softmax and spills (207MB scratch traffic).
// bb: gt[0,8192) vt[8192,12288) vlo[12288,16384) w1pk[16384,53248)
//     w2pk[53248,126976) w3pk[126976,200704)
__global__ void pack_k(const float* __restrict__ wb, u16* __restrict__ bb){
  int i = blockIdx.x * 256 + threadIdx.x;   // grid exact: 768*256 = 196608
  if (i < 4096){                                      // gt hi+lo (identity rows)
    const int d = i >> 6, c = i & 63;
    const float* __restrict__ K = wb + 4096;
    const float* __restrict__ Q = wb;
    float s = 0.f;
#pragma unroll
    for (int e = 0; e < 64; ++e) s = fmaf(K[d * 64 + e], Q[c * 64 + e], s);
    const u16 hi = f2bf(s);
    bb[i] = hi;
    bb[4096 + i] = f2bf(s - bf2f(hi));
    return;
  }
  i -= 4096;
  if (i < 4096){                                      // vt hi: vt[o][c] = V[c][o]
    const int o = i >> 6, c = i & 63;
    bb[8192 + i] = f2bf(wb[8192 + c * 64 + o]);
    return;
  }
  i -= 4096;
  if (i < 4096){                                      // vt lo (unused)
    const int o = i >> 6, c = i & 63;
    const float v = wb[8192 + c * 64 + o];
    bb[12288 + i] = f2bf(v - bf2f(f2bf(v)));
    return;
  }
  i -= 4096;
  if (i < 36864){                                     // w1pk (18 chunks)
    const int chunk = i >> 11, rr = i & 2047, co = rr >> 5, kkp = rr & 31;
    const int slot = (kkp >> 3) ^ ((co >> 1) & 3), kk = slot * 8 + (kkp & 7);
    const int tap = chunk >> 1, ci = (chunk & 1) * 32 + kk;
    bb[16384 + i] = f2bf(wb[12288 + (tap * 64 + ci) * 64 + co]);
    return;
  }
  i -= 36864;
  if (i < 73728){                                     // w2pk [2 halves][18 chunks]
    const int half = i / 36864, i2 = i - half * 36864;
    const int chunk = i2 >> 11, rr = i2 & 2047, co = rr >> 5, kkp = rr & 31;
    const int slot = (kkp >> 3) ^ ((co >> 1) & 3), kk = slot * 8 + (kkp & 7);
    const int tap = chunk >> 1, ci = (chunk & 1) * 32 + kk;
    bb[53248 + i] = f2bf(wb[49216 + (tap * 64 + ci) * 128 + half * 64 + co]);
    return;
  }
  i -= 73728;
  {                                                   // w3pk (36 chunks: tap*4 + ci_chunk)
    const int chunk = i >> 11, rr = i & 2047, co = rr >> 5, kkp = rr & 31;
    const int slot = (kkp >> 3) ^ ((co >> 1) & 3), kk = slot * 8 + (kkp & 7);
    const int tap = chunk >> 2, ci = (chunk & 3) * 32 + kk;
    bb[126976 + i] = f2bf(wb[123072 + (tap * 128 + ci) * 64 + co]);
  }
}

// ---------------- halo staging into swizzled LDS ----------------
template<int ROWS, int CIN, int STRIDE>
DEVINL void stage_tile(const u16* __restrict__ img_base, int h0, int w0, u16* lds){
  constexpr int CH8 = CIN / 8;
  constexpr int NCH = ROWS * 66 * CH8;
  for (int idx = threadIdx.x; idx < NCH; idx += 256){
    const int row  = idx / (66 * CH8);
    const int rem  = idx - row * 66 * CH8;
    const int col  = rem / CH8;
    const int slot = rem - col * CH8;
    const int hi = h0 + row - 1, wi = w0 + col - 1;
    uint4 v = make_uint4(0u, 0u, 0u, 0u);
    if (hi >= 0 && hi < 128 && wi >= 0 && wi < 128)
      v = *(const uint4*)(img_base + (size_t)(hi * 128 + wi) * STRIDE + slot * 8);
    const int dst = (row * 66 + col) * CIN + ((slot ^ (col & 7)) << 3);
    *(uint4*)(lds + dst) = v;
  }
}

// ---------------- coalesced conv epilogue (TROWS=2, runtime out dtype) ----------------
template<int COUT_FULL, bool RES>
DEVINL void conv_epilogue2(f32x4 acc[2][4], u16* scratch, const u16* __restrict__ res,
                           void* __restrict__ out, int img, int h0, int w0, int co0,
                           int wv, int l15, int lk, int mout)
{
  float* tl = (float*)scratch;            // 128 px x 72 f32 = 36864 B
  const int lane = threadIdx.x & 63;
  __syncthreads();                        // all halo reads done (tl aliases halo)
  const int pbase = (wv >> 1) * 64 + (wv & 1) * 32;
#pragma unroll
  for (int at = 0; at < 2; ++at)
#pragma unroll
    for (int nt = 0; nt < 4; ++nt)
#pragma unroll
      for (int reg = 0; reg < 4; ++reg)
        tl[(pbase + at * 16 + lk * 4 + reg) * 72 + nt * 16 + l15] =
            fmaxf(acc[at][nt][reg], 0.f);
  __syncthreads();

  if (mout == 0){
#pragma unroll
    for (int k = 0; k < 8; ++k){
      const int pxl = k * 16 + wv * 4 + (lane >> 4);
      const int c4  = (lane & 15) * 4;
      const int row = pxl >> 6, col = pxl & 63;
      const size_t gpx = (size_t)img * 16384 + (size_t)(h0 + row) * 128 + w0 + col;
      float4 v = *(const float4*)(tl + pxl * 72 + c4);
      if (RES){
        const uint2 r = *(const uint2*)(res + gpx * 64 + c4);
        v.x += bf2f((u16)(r.x & 0xffff)); v.y += bf2f((u16)(r.x >> 16));
        v.z += bf2f((u16)(r.y & 0xffff)); v.w += bf2f((u16)(r.y >> 16));
      }
      *(float4*)((float*)out + gpx * 64 + c4) = v;
    }
  } else {
#pragma unroll
    for (int j = 0; j < 4; ++j){
      const int pxl = j * 32 + wv * 8 + (lane >> 3);
      const int c8  = (lane & 7) * 8;
      const int row = pxl >> 6, col = pxl & 63;
      const size_t gpx = (size_t)img * 16384 + (size_t)(h0 + row) * 128 + w0 + col;
      const float* tp = tl + pxl * 72 + c8;
      const float4 a = *(const float4*)tp;
      const float4 b = *(const float4*)(tp + 4);
      float v0=a.x, v1=a.y, v2=a.z, v3=a.w, v4=b.x, v5=b.y, v6=b.z, v7=b.w;
      if (RES){
        const uint4 r = *(const uint4*)(res + gpx * 64 + c8);
        v0 += bf2f((u16)(r.x & 0xffff)); v1 += bf2f((u16)(r.x >> 16));
        v2 += bf2f((u16)(r.y & 0xffff)); v3 += bf2f((u16)(r.y >> 16));
        v4 += bf2f((u16)(r.z & 0xffff)); v5 += bf2f((u16)(r.z >> 16));
        v6 += bf2f((u16)(r.w & 0xffff)); v7 += bf2f((u16)(r.w >> 16));
      }
      uint4 o;
      o.x = pack2(v0, v1); o.y = pack2(v2, v3);
      o.z = pack2(v4, v5); o.w = pack2(v6, v7);
      *(uint4*)((u16*)out + gpx * COUT_FULL + co0 + c8) = o;
    }
  }
}

// ---------------- fused 3x3 pixel attention (r19-proven form) ----------------
__global__ __launch_bounds__(256, 4)
void attn_mfma(const u16* __restrict__ xraw, const u16* __restrict__ xcv,
               const u16* __restrict__ gt, const u16* __restrict__ vt,
               u16* __restrict__ tb, const uint32* __restrict__ flag)
{
  __shared__ __align__(16) u16 xh[3 * 66 * 64];
  u16* yl  = xh;                   // aliases halo row 0
  u16* yl2 = xh + 2 * 66 * 64;     // aliases halo row 2
  const int bx0 = blockIdx.x;
  const int bx = (bx0 & 7) * 256 + (bx0 >> 3);   // XCD-chunked swizzle (2048 wgs)
  const int img = bx >> 8, h = (bx >> 1) & 127, w0 = (bx & 1) * 64;
  const int p0 = img * 16384 + h * 128 + w0;
  const u16* __restrict__ xsrc = (*flag != 0u) ? xraw : xcv;
  stage_tile<3, 64, 64>(xsrc + (size_t)img * 16384 * 64, h, w0, xh);
  __syncthreads();   // sync1

  const int lane = threadIdx.x & 63, wv = threadIdx.x >> 6;
  const int l15 = lane & 15, lk = lane >> 4;
  const int pxm = wv * 16 + l15;

  f32x4 racc[4];
#pragma unroll
  for (int nt = 0; nt < 4; ++nt) racc[nt] = (f32x4){0.f, 0.f, 0.f, 0.f};
#pragma unroll
  for (int half = 0; half < 2; ++half){
#pragma unroll
    for (int ks = 0; ks < 2; ++ks){
      const int colq = pxm + 1;
      const int slot = ks * 4 + lk;
      const s16x8 bx_ = *(const s16x8*)&xh[(66 + colq) * 64 + ((slot ^ (colq & 7)) << 3)];
#pragma unroll
      for (int nt = 0; nt < 4; ++nt){
        const s16x8 ag = *(const s16x8*)(gt + half * 4096 +
                          (size_t)(nt * 16 + l15) * 64 + ks * 32 + lk * 8);
        racc[nt] = MFMA16(ag, bx_, racc[nt]);
      }
    }
  }

  float sc[9];
#pragma unroll
  for (int n = 0; n < 9; ++n){
    const int tr = n / 3, tc = n % 3;
    const int col = pxm + tc;
    const u16* xr = &xh[(tr * 66 + col) * 64];
    float s = 0.f;
#pragma unroll
    for (int nt = 0; nt < 4; ++nt){
      const int slot = nt * 2 + (lk >> 1);
      const s16x4 v = *(const s16x4*)&xr[((slot ^ (col & 7)) << 3) + (lk & 1) * 4];
#pragma unroll
      for (int j = 0; j < 4; ++j)
        s = fmaf(bf2f((u16)v[j]), racc[nt][j], s);
    }
    sc[n] = s;
  }
#pragma unroll
  for (int n = 0; n < 9; ++n){
    sc[n] += __shfl_xor(sc[n], 16);
    sc[n] += __shfl_xor(sc[n], 32);
  }

  float mx = sc[0];
#pragma unroll
  for (int n = 1; n < 9; ++n) mx = fmaxf(mx, sc[n]);
  float sum = 0.f;
#pragma unroll
  for (int n = 0; n < 9; ++n){
    const float e = __expf(sc[n] - mx);
    sc[n] = e; sum += e;
  }
  const float inv = 1.f / sum;
#pragma unroll
  for (int n = 0; n < 9; ++n) sc[n] *= inv;

  float y[16];
#pragma unroll
  for (int j = 0; j < 16; ++j) y[j] = 0.f;
#pragma unroll
  for (int n = 0; n < 9; ++n){
    const int tr = n / 3, tc = n % 3;
    const int col = pxm + tc;
    const u16* xr = &xh[(tr * 66 + col) * 64];
    const float a = sc[n];
#pragma unroll
    for (int sl = 0; sl < 2; ++sl){
      const int slot = lk * 2 + sl;
      const s16x8 v = *(const s16x8*)&xr[(slot ^ (col & 7)) << 3];
#pragma unroll
      for (int j = 0; j < 8; ++j)
        y[sl * 8 + j] = fmaf(a, bf2f((u16)v[j]), y[sl * 8 + j]);
    }
  }

  __syncthreads();   // sync3: all xh row-0/2 reads complete before alias writes

#pragma unroll
  for (int sl = 0; sl < 2; ++sl){
    uint32 hwd[4], lwd[4];
#pragma unroll
    for (int j = 0; j < 4; ++j){
      const float a = y[sl * 8 + 2 * j], b = y[sl * 8 + 2 * j + 1];
      const u16 ha = f2bf(a), hb = f2bf(b);
      hwd[j] = (uint32)ha | ((uint32)hb << 16);
      lwd[j] = (uint32)f2bf(a - bf2f(ha)) | ((uint32)f2bf(b - bf2f(hb)) << 16);
    }
    const int slot = lk * 2 + sl;
    const int off = pxm * 64 + ((slot ^ (pxm & 7)) << 3);
    *(uint4*)&yl [off] = make_uint4(hwd[0], hwd[1], hwd[2], hwd[3]);
    *(uint4*)&yl2[off] = make_uint4(lwd[0], lwd[1], lwd[2], lwd[3]);
  }

  __syncthreads();   // sync4: y visible before PV reads

  f32x4 tacc[4];
#pragma unroll
  for (int nt = 0; nt < 4; ++nt) tacc[nt] = (f32x4){0.f, 0.f, 0.f, 0.f};
#pragma unroll
  for (int half = 0; half < 2; ++half){
    const u16* yb = half ? yl2 : yl;
#pragma unroll
    for (int ks = 0; ks < 2; ++ks){
      const int px = wv * 16 + l15;
      const int slot = ks * 4 + lk;
      const s16x8 af = *(const s16x8*)&yb[px * 64 + ((slot ^ (px & 7)) << 3)];
#pragma unroll
      for (int nt = 0; nt < 4; ++nt){
        const s16x8 bf = *(const s16x8*)(vt + (size_t)(nt * 16 + l15) * 64 + ks * 32 + lk * 8);
        tacc[nt] = MFMA16(af, bf, tacc[nt]);
      }
    }
  }
#pragma unroll
  for (int nt = 0; nt < 4; ++nt){
#pragma unroll
    for (int reg = 0; reg < 4; ++reg){
      const int pxo = wv * 16 + lk * 4 + reg;
      const int co = nt * 16 + l15;
      const int col = pxo + 1;
      const int elem = (66 + col) * 64 + (((co >> 3) ^ (col & 7)) << 3) + (co & 7);
      tb[(size_t)(p0 + pxo) * 64 + co] = f2bf(bf2f(xh[elem]) + tacc[nt][reg]);
    }
  }
}

// ---------------- conv1/conv2 (CIN=64): TROWS=2, A from LDS halo, B in registers ----------------
template<int COUT_FULL, bool RES>
__global__ __launch_bounds__(256)
void conv_mfma(const u16* __restrict__ in, const u16* __restrict__ wpk,
               const float* __restrict__ bias, const u16* __restrict__ res,
               void* __restrict__ out)
{
  __shared__ __align__(16) u16 xh[18432];         // 36864 B: halo 4x66x64 + epi scratch

  const int bx0 = blockIdx.x;
  const int bx  = (bx0 & 7) * 128 + (bx0 >> 3);   // XCD-chunked swizzle (1024 wgs)
  const int img = bx >> 7;
  const int rem = bx & 127;
  const int h0  = (rem >> 1) * 2;
  const int w0  = (rem & 1) * 64;
  const int co0 = blockIdx.y * 64;
  const u16* __restrict__ wp = wpk + (size_t)blockIdx.y * 18 * 2048;

  stage_tile<4, 64, 64>(in + (size_t)img * 16384 * 64, h0, w0, xh);
  __syncthreads();

  const int lane = threadIdx.x & 63, wv = threadIdx.x >> 6;
  const int l15 = lane & 15, lk = lane >> 4;
  const int r   = wv >> 1, c0l = (wv & 1) * 32;

  f32x4 acc[2][4];
#pragma unroll
  for (int nt = 0; nt < 4; ++nt){
    const float b = bias[co0 + nt * 16 + l15];
#pragma unroll
    for (int at = 0; at < 2; ++at) acc[at][nt] = (f32x4){b, b, b, b};
  }

  auto loadB = [&](int ck, s16x8* bb){
#pragma unroll
    for (int nt = 0; nt < 4; ++nt){
      const int co = nt * 16 + l15;
      bb[nt] = *(const s16x8*)(wp + (size_t)ck * 2048 + co * 32 +
                               ((lk ^ ((co >> 1) & 3)) << 3));
    }
  };
  auto doM = [&](int it, s16x8* bb){
    const int tap = it >> 1, ks = it & 1;
    const int tr = tap / 3, tc = tap - tr * 3;
    const int slot = ks * 4 + lk;
    s16x8 av[2];
#pragma unroll
    for (int at = 0; at < 2; ++at){
      const int col = c0l + at * 16 + l15 + tc;
      av[at] = *(const s16x8*)&xh[((r + tr) * 66 + col) * 64 + ((slot ^ (col & 7)) << 3)];
    }
#pragma unroll
    for (int at = 0; at < 2; ++at)
#pragma unroll
      for (int nt = 0; nt < 4; ++nt)
        acc[at][nt] = MFMA16(av[at], bb[nt], acc[at][nt]);
  };

  s16x8 b0[4], b1[4];
  loadB(0, b0);
  loadB(1, b1);
#pragma unroll 1
  for (int it = 0; it < 18; it += 2){
    doM(it, b0);
    if (it + 2 < 18) loadB(it + 2, b0);
    doM(it + 1, b1);
    if (it + 3 < 18) loadB(it + 3, b1);
  }

  conv_epilogue2<COUT_FULL, RES>(acc, xh, res, out, img, h0, w0, co0, wv, l15, lk, 1);
}

// ---------------- conv3 (CIN=128): TROWS=2, two ci-half phases, merged out-dtype ----------------
__global__ __launch_bounds__(256)
void conv3_mfma(const u16* __restrict__ in, const u16* __restrict__ wpk,
                const float* __restrict__ bias, const u16* __restrict__ res,
                void* __restrict__ out, const uint32* __restrict__ flag)
{
  const int mout = (*flag != 0u) ? 1 : 0;
  __shared__ __align__(16) u16 xh[18432];         // 36864 B

  const int bx0 = blockIdx.x;
  const int bx  = (bx0 & 7) * 128 + (bx0 >> 3);   // XCD-chunked swizzle (1024 wgs)
  const int img = bx >> 7;
  const int rem = bx & 127;
  const int h0  = (rem >> 1) * 2;
  const int w0  = (rem & 1) * 64;

  const int lane = threadIdx.x & 63, wv = threadIdx.x >> 6;
  const int l15 = lane & 15, lk = lane >> 4;
  const int r   = wv >> 1, c0l = (wv & 1) * 32;

  f32x4 acc[2][4];
#pragma unroll
  for (int nt = 0; nt < 4; ++nt){
    const float b = bias[nt * 16 + l15];
#pragma unroll
    for (int at = 0; at < 2; ++at) acc[at][nt] = (f32x4){b, b, b, b};
  }

  auto loadB = [&](int ck, s16x8* bb){
#pragma unroll
    for (int nt = 0; nt < 4; ++nt){
      const int co = nt * 16 + l15;
      bb[nt] = *(const s16x8*)(wpk + (size_t)ck * 2048 + co * 32 +
                               ((lk ^ ((co >> 1) & 3)) << 3));
    }
  };
  auto doM = [&](int it, s16x8* bb){
    const int tap = it >> 1, ks = it & 1;
    const int tr = tap / 3, tc = tap - tr * 3;
    const int slot = ks * 4 + lk;
    s16x8 av[2];
#pragma unroll
    for (int at = 0; at < 2; ++at){
      const int col = c0l + at * 16 + l15 + tc;
      av[at] = *(const s16x8*)&xh[((r + tr) * 66 + col) * 64 + ((slot ^ (col & 7)) << 3)];
    }
#pragma unroll
    for (int at = 0; at < 2; ++at)
#pragma unroll
      for (int nt = 0; nt < 4; ++nt)
        acc[at][nt] = MFMA16(av[at], bb[nt], acc[at][nt]);
  };
  auto chunkOf = [&](int it, int half){
    return ((it >> 1) << 2) + half * 2 + (it & 1);   // tap*4 + half*2 + ks
  };

#pragma unroll 1
  for (int half = 0; half < 2; ++half){
    if (half) __syncthreads();            // all waves' reads of phase-0 halo done
    stage_tile<4, 64, 128>(in + (size_t)img * 16384 * 128 + half * 64, h0, w0, xh);
    __syncthreads();

    s16x8 b0[4], b1[4];
    loadB(chunkOf(0, half), b0);
    loadB(chunkOf(1, half), b1);
#pragma unroll 1
    for (int it = 0; it < 18; it += 2){
      doM(it, b0);
      if (it + 2 < 18) loadB(chunkOf(it + 2, half), b0);
      doM(it + 1, b1);
      if (it + 3 < 18) loadB(chunkOf(it + 3, half), b1);
    }
  }

  conv_epilogue2<64, true>(acc, xh, res, out, img, h0, w0, 0, wv, l15, lk, mout);
}

extern "C" void kernel_launch(void* const* d_in, const int* in_sizes, int n_in,
                              void* d_out, int out_size, void* d_ws, size_t ws_size,
                              hipStream_t stream)
{
  (void)in_sizes; (void)n_in; (void)out_size; (void)ws_size;

  char* ws = (char*)d_ws;
  float*  wblob = (float*)ws;                            // 196864 f32
  uint32* flag  = (uint32*)(ws + 983040);
  u16*    bb    = (u16*)(ws + (1u << 20));               // bf16 blob (200704 u16)
  u16*    gt   = bb;                                     // [2][64][64] hi/lo
  u16*    vt   = bb + 8192;                              // [64][64] hi
  u16*    w1pk = bb + 16384;                             // 18 x 4KB chunks
  u16*    w2pk = bb + 53248;                             // 2 x 18 x 4KB
  u16*    w3pk = bb + 126976;                            // 36 x 4KB

  u16*   c2 = (u16*)(ws + (size_t)2097152);              // 33.55 MB
  u16*   tb = (u16*)(ws + (size_t)35651584);             // 16.78 MB
  u16*   xb = (u16*)(ws + (size_t)52428800);             // 16.78 MB (fp32 mode)
  u16*   c1 = (u16*)(ws + (size_t)52428800);             // 16.78 MB (after attn)

  detect_k<<<1, 64, 0, stream>>>((const uint32*)d_in[0], flag);

  cvtall_k<<<769, 256, 0, stream>>>(d_in[1], d_in[2], d_in[3], d_in[4], d_in[5],
                                    d_in[6], d_in[7], d_in[8], d_in[9], wblob, flag);

  xcvt_k<<<512, 256, 0, stream>>>(d_in[0], xb, flag);    // fp32 mode only

  pack_k<<<768, 256, 0, stream>>>(wblob, bb);            // gt + vt + conv W

  attn_mfma<<<2048, 256, 0, stream>>>((const u16*)d_in[0], xb, gt, vt, tb, flag);

  conv_mfma<64, false><<<dim3(1024, 1), 256, 0, stream>>>(
      tb, w1pk, wblob + 49152, nullptr, c1);
  conv_mfma<128, false><<<dim3(1024, 2), 256, 0, stream>>>(
      c1, w2pk, wblob + 122944, nullptr, c2);
  conv3_mfma<<<1024, 256, 0, stream>>>(
      c2, w3pk, wblob + 196800, tb, d_out, flag);
}